// Round 16
// baseline (3219.081 us; speedup 1.0000x reference)
//
#include <hip/hip_runtime.h>
#include <hip/hip_bf16.h>

#define B_  256
#define T_  1024
#define D_  256
#define H_  512
#define G_  2048   // 4*H
#define KT_ 768    // H + D

// ws layout (bytes)
#define WPACK_OFF 0                        // 2048*768*2 = 3145728
#define BIAS_OFF  3145728                  // 2048*4     = 8192
#define H0_OFF    (BIAS_OFF + 8192)        // 256*512*2  = 262144
#define H1_OFF    (H0_OFF + 262144)
#define C_OFF     (H1_OFF + 262144)        // 512KB: fallback cbuf
#define FLAG_OFF  C_OFF                    // flags alias cbuf (paths exclusive):
                                           // 256 flags x 32 uints = 32KB

typedef __attribute__((ext_vector_type(8))) short bf16x8;
typedef __attribute__((ext_vector_type(4))) float f32x4;
typedef __attribute__((ext_vector_type(4))) unsigned int u32x4;   // asm-safe 16B vector

__device__ __forceinline__ unsigned short f2bf(float f) {
    unsigned int u = __float_as_uint(f);
    u = (u + 0x7fffu + ((u >> 16) & 1u)) >> 16;   // RNE
    return (unsigned short)u;
}
__device__ __forceinline__ float bf2f(unsigned short s) {
    return __uint_as_float(((unsigned int)s) << 16);
}
__device__ __forceinline__ float sigm(float v) { return 1.0f / (1.0f + __expf(-v)); }
__device__ __forceinline__ float tanh_(float v) { return 2.0f / (1.0f + __expf(-2.0f * v)) - 1.0f; }

// ---- prep: pack [W_hh | W_ih] rows into bf16 Wpack[2048][768] ----
__global__ __launch_bounds__(256) void build_wpack(const float* __restrict__ Whh,
                                                   const float* __restrict__ Wih,
                                                   unsigned short* __restrict__ wpack) {
    int idx = blockIdx.x * 256 + threadIdx.x;      // 0..196607, each = 8 elems
    int g = idx / 96, cc = idx % 96, k = cc * 8;
    const float* src = (k < H_) ? (Whh + (size_t)g * H_ + k)
                                : (Wih + (size_t)g * D_ + (k - H_));
    union { unsigned short us[8]; uint4 v; } u;
#pragma unroll
    for (int i = 0; i < 8; ++i) u.us[i] = f2bf(src[i]);
    *(uint4*)(wpack + (size_t)idx * 8) = u.v;
}

// ---- prep: zero h0/h1/c(+aliased flags), build bias ----
__global__ __launch_bounds__(256) void init_misc(const float* __restrict__ bih,
                                                 const float* __restrict__ bhh,
                                                 float* __restrict__ bias,
                                                 unsigned int* __restrict__ zreg,
                                                 unsigned int* __restrict__ flags) {
    int gid = blockIdx.x * 256 + threadIdx.x;      // grid 1024 -> 262144
    zreg[gid] = 0u;                                // h0+h1+c region (1 MB, covers flags)
    if (gid < G_) bias[gid] = bih[gid] + bhh[gid];
    if (gid < 16384) flags[gid] = 0u;
}

// ============ persistent cooperative LSTM ============
// grid 256: rg = bid&15 (rowgroup, 16 batch rows), cg = bid>>4 (32 j-cols).
// 512 threads = 8 waves; wave w: gate g = w>>1, K-half kh = w&1 (even/odd ks).
// Each wave reads ONE A-fragment per ks and issues 2 MFMAs (both 16-col
// j-tiles) -> As LDS reads halve vs (gate, col-half) split. W fragments:
// 12 ks x 2 j-tiles = 24 bf16x8 = 96 VGPR, loaded once. c: 1 reg/thread.
// h protocol (r15-proven instruction set, 4 barriers/step):
//   producer tail (DEFERRED DRAIN): G epilogue -> Hs -> bar4 -> wave 0
//     ISSUES the 1KB tile stores (2x8B relaxed) and continues; it skips
//     A-staging, passes bar1 immediately, and after B1 drains ITS OWN vmcnt
//     and publishes the block flag -- the store RT hides under A+B1.
//   consumer head: ALL waves poll the 16 block flags (relaxed), then load h
//     with sc0 sc1 (LLC-direct) -- no acquire, no inv, x stays cached.
//   Deadlock-free: every block publishes its flag before polling.
// Pc[2][4][16][34] partial sums over kh; epilogue sums both halves.
// LDS padded (volatile) so 1 block/CU -> 256 blocks on 256 CUs.
__global__ __launch_bounds__(512, 2) void lstm_persist(
    const float* __restrict__ x,
    const unsigned short* __restrict__ wpack,
    const float* __restrict__ bias,
    unsigned short* __restrict__ h0,
    unsigned short* __restrict__ h1,
    unsigned int* __restrict__ flags)
{
    __shared__ __align__(16) unsigned char As[16 * 1536];   // [16 rows][768 k] bf16, swizzled
    __shared__ float Pc[2][4][16][34];                       // [kh][gate][row][j]
    __shared__ __align__(16) unsigned short Hs[16][32];      // new h tile (bf16)
    __shared__ unsigned char lds_pad[40 * 1024];             // force 1 block/CU

    const int tid  = threadIdx.x;
    const int lane = tid & 63, w = tid >> 6;
    const int g = w >> 1, kh = w & 1;
    const int rg = blockIdx.x & 15, cg = blockIdx.x >> 4;
    const int r0 = rg * 16;

    ((volatile unsigned char*)lds_pad)[tid] = 0;   // keep pad alive

    // ---- load this wave's W fragments (12 ks x 2 j-tiles), once ----
    bf16x8 bfr[24];
    {
#pragma unroll
        for (int i = 0; i < 12; ++i) {
            int ks = 2 * i + kh;
#pragma unroll
            for (int jt2 = 0; jt2 < 2; ++jt2) {
                const unsigned short* wrow = wpack
                    + (size_t)(g * H_ + cg * 32 + jt2 * 16 + (lane & 15)) * KT_
                    + ((lane >> 4) * 8) + ks * 32;
                bfr[i * 2 + jt2] = *(const bf16x8*)wrow;
            }
        }
    }

    // ---- per-thread epilogue constants (16 rows x 32 j = 512 threads) ----
    const int erow = tid >> 5;        // 0..15
    const int ejj  = tid & 31;        // 0..31
    const float bI = bias[0 * H_ + cg * 32 + ejj];
    const float bF = bias[1 * H_ + cg * 32 + ejj];
    const float bG = bias[2 * H_ + cg * 32 + ejj];
    const float bO = bias[3 * H_ + cg * 32 + ejj];
    float c_reg = 0.f;

    const int arow = lane & 15;            // A-tile row
    const int koff = (lane >> 4) * 16;     // byte offset within 64B k-step
    const int asw  = (arow & 7) << 4;

    // ---- x staging: waves 1-7 only (448 threads, 512 chunks of 8 floats) ----
    const int tt  = tid - 64;
    const int xc0 = tt, xc1 = tt + 448;
    const float* xb0 = nullptr;
    const float* xb1 = nullptr;
    float4 p0a, p0b, p1a, p1b;
    if (tid >= 64) {
        xb0 = x + (size_t)(r0 + (xc0 >> 5)) * T_ * D_ + (xc0 & 31) * 8;
        p0a = *(const float4*)(xb0);
        p0b = *(const float4*)(xb0 + 4);
        if (xc1 < 512) {
            xb1 = x + (size_t)(r0 + (xc1 >> 5)) * T_ * D_ + (xc1 & 31) * 8;
            p1a = *(const float4*)(xb1);
            p1b = *(const float4*)(xb1 + 4);
        }
    }

    unsigned int* myflag   = flags + (size_t)(rg * 16 + cg) * 32;
    unsigned int* pollflag = flags + (size_t)(rg * 16 + (lane & 15)) * 32;

    for (int t = 0; t < T_; ++t) {
        const unsigned short* hin = (t & 1) ? h1 : h0;
        unsigned short*      hout = (t & 1) ? h0 : h1;

        // A: waves 1-7 stage x(t) -> As.x (k 512..767); prefetch x(t+1).
        //    Wave 0 skips (its H stores from iter t-1 are in flight).
        if (tid >= 64) {
            {
                union { unsigned short us[8]; uint4 v; } u;
                u.us[0] = f2bf(p0a.x); u.us[1] = f2bf(p0a.y); u.us[2] = f2bf(p0a.z); u.us[3] = f2bf(p0a.w);
                u.us[4] = f2bf(p0b.x); u.us[5] = f2bf(p0b.y); u.us[6] = f2bf(p0b.z); u.us[7] = f2bf(p0b.w);
                int r = xc0 >> 5, s = xc0 & 31;
                *(uint4*)(As + ((r * 1536 + 1024 + s * 16) ^ ((r & 7) << 4))) = u.v;
            }
            if (xc1 < 512) {
                union { unsigned short us[8]; uint4 v; } u;
                u.us[0] = f2bf(p1a.x); u.us[1] = f2bf(p1a.y); u.us[2] = f2bf(p1a.z); u.us[3] = f2bf(p1a.w);
                u.us[4] = f2bf(p1b.x); u.us[5] = f2bf(p1b.y); u.us[6] = f2bf(p1b.z); u.us[7] = f2bf(p1b.w);
                int r = xc1 >> 5, s = xc1 & 31;
                *(uint4*)(As + ((r * 1536 + 1024 + s * 16) ^ ((r & 7) << 4))) = u.v;
            }
            if (t + 1 < T_) {
                const float* sp = xb0 + (size_t)(t + 1) * D_;
                p0a = *(const float4*)(sp);
                p0b = *(const float4*)(sp + 4);
                if (xc1 < 512) {
                    sp = xb1 + (size_t)(t + 1) * D_;
                    p1a = *(const float4*)(sp);
                    p1b = *(const float4*)(sp + 4);
                }
            }
        }
        __syncthreads();   // bar1: As.x ready; orders E(t-1) reads vs D(t) writes

        // B1: x-part MFMAs, first half (i = 8,9 -> ks 16+kh, 18+kh)
        f32x4 acc[2][2];   // [jt2][i&1]
#pragma unroll
        for (int a = 0; a < 2; ++a) { acc[0][a] = (f32x4){0,0,0,0}; acc[1][a] = (f32x4){0,0,0,0}; }
#pragma unroll
        for (int i = 8; i < 10; ++i) {
            int ks = 2 * i + kh;
            bf16x8 av = *(const bf16x8*)(As + ((arow * 1536 + ks * 64 + koff) ^ asw));
            acc[0][i & 1] = __builtin_amdgcn_mfma_f32_16x16x32_bf16(av, bfr[i * 2 + 0], acc[0][i & 1], 0, 0, 0);
            acc[1][i & 1] = __builtin_amdgcn_mfma_f32_16x16x32_bf16(av, bfr[i * 2 + 1], acc[1][i & 1], 0, 0, 0);
        }

        // Deferred producer tail: wave 0 drains its H(t-1) stores (they've had
        // A+bar1+B1 to land) and publishes the block flag for step t.
        if (w == 0 && t > 0) {
            asm volatile("s_waitcnt vmcnt(0)" ::: "memory");
            if (lane == 0)
                __hip_atomic_store(myflag, (unsigned)t, __ATOMIC_RELAXED,
                                   __HIP_MEMORY_SCOPE_AGENT);
        }

        // C: ALL waves poll the 16 block flags (relaxed; lanes 16-63 mirror).
        if (t > 0) {
            while (true) {
                unsigned int f = __hip_atomic_load(pollflag, __ATOMIC_RELAXED,
                                                   __HIP_MEMORY_SCOPE_AGENT);
                if (__all((int)(f >= (unsigned)t))) break;
                __builtin_amdgcn_s_sleep(1);
            }
        }

        // D: issue LLC-direct 16B h loads (2/thread, 16KB) into regs; overlap
        //    the remaining x-part MFMAs (i = 10,11); then stage to As.h.
        {
            u32x4 hv0, hv1;
            {
                int c = tid;                      // chunks 0..511
                int row = c >> 6, off = c & 63;
                const u32x4* pp0 = (const u32x4*)(hin + (size_t)(r0 + row) * H_ + off * 8);
                c = 512 + tid;
                row = c >> 6; off = c & 63;
                const u32x4* pp1 = (const u32x4*)(hin + (size_t)(r0 + row) * H_ + off * 8);
                asm volatile("global_load_dwordx4 %0, %2, off sc0 sc1\n\t"
                             "global_load_dwordx4 %1, %3, off sc0 sc1"
                             : "=&v"(hv0), "=&v"(hv1)
                             : "v"(pp0), "v"(pp1));
            }
#pragma unroll
            for (int i = 10; i < 12; ++i) {
                int ks = 2 * i + kh;
                bf16x8 av = *(const bf16x8*)(As + ((arow * 1536 + ks * 64 + koff) ^ asw));
                acc[0][i & 1] = __builtin_amdgcn_mfma_f32_16x16x32_bf16(av, bfr[i * 2 + 0], acc[0][i & 1], 0, 0, 0);
                acc[1][i & 1] = __builtin_amdgcn_mfma_f32_16x16x32_bf16(av, bfr[i * 2 + 1], acc[1][i & 1], 0, 0, 0);
            }
            asm volatile("s_waitcnt vmcnt(0)" ::: "memory");
            __builtin_amdgcn_sched_barrier(0);
            {
                int c = tid;
                int row = c >> 6, off = c & 63;
                *(u32x4*)(As + ((row * 1536 + off * 16) ^ ((row & 7) << 4))) = hv0;
                c = 512 + tid;
                row = c >> 6; off = c & 63;
                *(u32x4*)(As + ((row * 1536 + off * 16) ^ ((row & 7) << 4))) = hv1;
            }
        }
        __syncthreads();   // bar2: As.h ready

        // E: h-part MFMAs (i = 0..7 -> 8 ks of this K-half)
#pragma unroll
        for (int i = 0; i < 8; ++i) {
            int ks = 2 * i + kh;
            bf16x8 av = *(const bf16x8*)(As + ((arow * 1536 + ks * 64 + koff) ^ asw));
            acc[0][i & 1] = __builtin_amdgcn_mfma_f32_16x16x32_bf16(av, bfr[i * 2 + 0], acc[0][i & 1], 0, 0, 0);
            acc[1][i & 1] = __builtin_amdgcn_mfma_f32_16x16x32_bf16(av, bfr[i * 2 + 1], acc[1][i & 1], 0, 0, 0);
        }
        // F: dump partial gate tile (C layout: col=lane&15, row=(lane>>4)*4+reg)
#pragma unroll
        for (int reg = 0; reg < 4; ++reg) {
            int crow = ((lane >> 4) * 4) + reg;
            Pc[kh][g][crow][(lane & 15)]      = acc[0][0][reg] + acc[0][1][reg];
            Pc[kh][g][crow][16 + (lane & 15)] = acc[1][0][reg] + acc[1][1][reg];
        }
        __syncthreads();   // bar3: Pc ready

        // G: cell update; thread owns (erow, ejj); sum both K-halves;
        //    c stays in register; write h to Hs for the wave-0 tail.
        {
            float gi = Pc[0][0][erow][ejj] + Pc[1][0][erow][ejj] + bI;
            float gf = Pc[0][1][erow][ejj] + Pc[1][1][erow][ejj] + bF;
            float gg = Pc[0][2][erow][ejj] + Pc[1][2][erow][ejj] + bG;
            float go = Pc[0][3][erow][ejj] + Pc[1][3][erow][ejj] + bO;
            float I = sigm(gi), F = sigm(gf), Gv = tanh_(gg), O = sigm(go);
            c_reg = F * c_reg + I * Gv;
            Hs[erow][ejj] = f2bf(O * tanh_(c_reg));
        }
        __syncthreads();   // bar4: Hs ready

        // H: wave 0 ISSUES the 1KB tile stores (16B/lane as 2x8B relaxed) and
        //    continues -- NO drain here. Drain+flag happen next iter after B1.
        if (tid < 64) {
            int row = tid >> 2, part = tid & 3;
            const unsigned long long* src = (const unsigned long long*)(&Hs[row][part * 8]);
            unsigned long long v0 = src[0], v1 = src[1];
            unsigned long long* dst = (unsigned long long*)(hout + (size_t)(r0 + row) * H_ + cg * 32 + part * 8);
            __hip_atomic_store(dst,     v0, __ATOMIC_RELAXED, __HIP_MEMORY_SCOPE_AGENT);
            __hip_atomic_store(dst + 1, v1, __ATOMIC_RELAXED, __HIP_MEMORY_SCOPE_AGENT);
        }
    }
    // final-step stores drain at kernel end (kernel completion is a release).
}

// ============ fallback per-step kernel (round-1, known passing) ============
__global__ __launch_bounds__(256) void lstm_step(const float* __restrict__ x,
                                                 const unsigned short* __restrict__ wpack,
                                                 const float* __restrict__ bias,
                                                 const unsigned short* __restrict__ hin,
                                                 unsigned short* __restrict__ hout,
                                                 float* __restrict__ cbuf,
                                                 int t) {
    __shared__ __align__(16) unsigned char As[64 * 1536];
    __shared__ __align__(16) unsigned char Ws[128 * 256];

    const int tid = threadIdx.x;
    const int w = tid >> 6, lane = tid & 63;
    const int r0 = blockIdx.x * 64;
    const int j0 = blockIdx.y * 32;

#pragma unroll
    for (int p = 0; p < 16; ++p) {
        int idx = p * 256 + tid;
        int row = idx >> 6, seg = idx & 63;
        uint4 v = *(const uint4*)(hin + (size_t)(r0 + row) * H_ + seg * 8);
        *(uint4*)(As + (((row * 1536) + seg * 16) ^ ((row & 7) << 4))) = v;
    }
#pragma unroll
    for (int p = 0; p < 8; ++p) {
        int idx = p * 256 + tid;
        int row = idx >> 5, seg = idx & 31;
        const float* sp = x + ((size_t)(r0 + row) * T_ + t) * D_ + seg * 8;
        float4 a = *(const float4*)sp;
        float4 b = *(const float4*)(sp + 4);
        union { unsigned short us[8]; uint4 v; } u;
        u.us[0] = f2bf(a.x); u.us[1] = f2bf(a.y); u.us[2] = f2bf(a.z); u.us[3] = f2bf(a.w);
        u.us[4] = f2bf(b.x); u.us[5] = f2bf(b.y); u.us[6] = f2bf(b.z); u.us[7] = f2bf(b.w);
        *(uint4*)(As + (((row * 1536) + 1024 + seg * 16) ^ ((row & 7) << 4))) = u.v;
    }
    __syncthreads();

    f32x4 acc[8];
#pragma unroll
    for (int i = 0; i < 8; ++i) acc[i] = (f32x4){0.f, 0.f, 0.f, 0.f};

    for (int kc = 0; kc < 6; ++kc) {
#pragma unroll
        for (int p = 0; p < 8; ++p) {
            int idx = p * 256 + tid;
            int n = idx >> 4, seg = idx & 15;
            int g = n >> 5, jj = n & 31;
            uint4 v = *(const uint4*)(wpack + (size_t)(g * H_ + j0 + jj) * KT_ + kc * 128 + seg * 8);
            *(uint4*)(Ws + (((n * 256) + seg * 16) ^ ((n & 7) << 4))) = v;
        }
        __syncthreads();
#pragma unroll
        for (int ks = 0; ks < 4; ++ks) {
            int row = w * 16 + (lane & 15);
            int kb = (kc * 128 + ks * 32 + ((lane >> 4) * 8)) * 2;
            bf16x8 av = *(const bf16x8*)(As + ((row * 1536 + kb) ^ ((row & 7) << 4)));
            int kwb = (ks * 32 + ((lane >> 4) * 8)) * 2;
#pragma unroll
            for (int nt = 0; nt < 8; ++nt) {
                int n = (nt >> 1) * 32 + (nt & 1) * 16 + (lane & 15);
                bf16x8 bv = *(const bf16x8*)(Ws + ((n * 256 + kwb) ^ ((n & 7) << 4)));
                acc[nt] = __builtin_amdgcn_mfma_f32_16x16x32_bf16(av, bv, acc[nt], 0, 0, 0);
            }
        }
        __syncthreads();
    }

#pragma unroll
    for (int jt = 0; jt < 2; ++jt) {
        int jc = j0 + jt * 16 + (lane & 15);
        float bi = bias[jc], bf = bias[H_ + jc], bg = bias[2 * H_ + jc], bo = bias[3 * H_ + jc];
        f32x4 ai = acc[0 * 2 + jt];
        f32x4 af = acc[1 * 2 + jt];
        f32x4 ag = acc[2 * 2 + jt];
        f32x4 ao = acc[3 * 2 + jt];
#pragma unroll
        for (int reg = 0; reg < 4; ++reg) {
            int rb = r0 + w * 16 + ((lane >> 4) * 4) + reg;
            float I = sigm(ai[reg] + bi);
            float F = sigm(af[reg] + bf);
            float Gv = tanh_(ag[reg] + bg);
            float O = sigm(ao[reg] + bo);
            size_t ci = (size_t)rb * H_ + jc;
            float cn = F * cbuf[ci] + I * Gv;
            cbuf[ci] = cn;
            hout[ci] = f2bf(O * tanh_(cn));
        }
    }
}

// ---- final: out = sigmoid(h @ W_out^T + b_out), [256,2] ----
__global__ __launch_bounds__(256) void classify(const unsigned short* __restrict__ hbuf,
                                                const float* __restrict__ Wout,
                                                const float* __restrict__ bout,
                                                float* __restrict__ out) {
    int r = threadIdx.x;
    float a0 = 0.f, a1 = 0.f;
    for (int kk = 0; kk < H_ / 8; ++kk) {
        union { unsigned short us[8]; uint4 v; } u;
        u.v = *(const uint4*)(hbuf + (size_t)r * H_ + kk * 8);
#pragma unroll
        for (int i = 0; i < 8; ++i) {
            float hf = bf2f(u.us[i]);
            int k = kk * 8 + i;
            a0 += hf * Wout[k];
            a1 += hf * Wout[H_ + k];
        }
    }
    out[r * 2 + 0] = sigm(a0 + bout[0]);
    out[r * 2 + 1] = sigm(a1 + bout[1]);
}

extern "C" void kernel_launch(void* const* d_in, const int* in_sizes, int n_in,
                              void* d_out, int out_size, void* d_ws, size_t ws_size,
                              hipStream_t stream) {
    const float* x    = (const float*)d_in[0];
    const float* Wih  = (const float*)d_in[1];
    const float* Whh  = (const float*)d_in[2];
    const float* bih  = (const float*)d_in[3];
    const float* bhh  = (const float*)d_in[4];
    const float* Wout = (const float*)d_in[5];
    const float* bout = (const float*)d_in[6];
    float* out = (float*)d_out;
    char* ws = (char*)d_ws;

    unsigned short* wpack = (unsigned short*)(ws + WPACK_OFF);
    float*          bias  = (float*)(ws + BIAS_OFF);
    unsigned short* h0    = (unsigned short*)(ws + H0_OFF);
    unsigned short* h1    = (unsigned short*)(ws + H1_OFF);
    float*          cbuf  = (float*)(ws + C_OFF);
    unsigned int*   flags = (unsigned int*)(ws + FLAG_OFF);   // aliases cbuf (exclusive paths)

    build_wpack<<<768, 256, 0, stream>>>(Whh, Wih, wpack);
    init_misc<<<1024, 256, 0, stream>>>(bih, bhh, bias, (unsigned int*)(ws + H0_OFF), flags);

    // persistent cooperative kernel; fall back to per-step launches if rejected
    const float* xa = x; const unsigned short* wa = wpack; const float* ba = bias;
    unsigned short* h0a = h0; unsigned short* h1a = h1; unsigned int* fa = flags;
    void* args[] = { (void*)&xa, (void*)&wa, (void*)&ba, (void*)&h0a, (void*)&h1a, (void*)&fa };
    hipError_t e = hipLaunchCooperativeKernel((const void*)lstm_persist,
                                              dim3(256), dim3(512), args, 0, stream);
    if (e != hipSuccess) {
        for (int t = 0; t < T_; ++t) {
            const unsigned short* hin = (t & 1) ? h1 : h0;
            unsigned short*      hout = (t & 1) ? h0 : h1;
            lstm_step<<<dim3(4, 16), 256, 0, stream>>>(x, wpack, bias, hin, hout, cbuf, t);
        }
    }
    classify<<<1, 256, 0, stream>>>(h0, Wout, bout, out);
}

// Round 17
// 2702.297 us; speedup vs baseline: 1.1912x; 1.1912x over previous
//
#include <hip/hip_runtime.h>
#include <hip/hip_bf16.h>

#define B_  256
#define T_  1024
#define D_  256
#define H_  512
#define G_  2048   // 4*H
#define KT_ 768    // H + D

// ws layout (bytes)
#define WPACK_OFF 0                        // 2048*768*2 = 3145728
#define BIAS_OFF  3145728                  // 2048*4     = 8192
#define H0_OFF    (BIAS_OFF + 8192)        // 256*512*2  = 262144
#define H1_OFF    (H0_OFF + 262144)
#define C_OFF     (H1_OFF + 262144)        // 512KB: fallback cbuf
#define FLAG_OFF  C_OFF                    // flags alias cbuf (paths exclusive):
                                           // 256 flags x 32 uints = 32KB

typedef __attribute__((ext_vector_type(8))) short bf16x8;
typedef __attribute__((ext_vector_type(4))) float f32x4;
typedef __attribute__((ext_vector_type(4))) unsigned int u32x4;   // asm-safe 16B vector

__device__ __forceinline__ unsigned short f2bf(float f) {
    unsigned int u = __float_as_uint(f);
    u = (u + 0x7fffu + ((u >> 16) & 1u)) >> 16;   // RNE
    return (unsigned short)u;
}
__device__ __forceinline__ float bf2f(unsigned short s) {
    return __uint_as_float(((unsigned int)s) << 16);
}
__device__ __forceinline__ float sigm(float v) { return 1.0f / (1.0f + __expf(-v)); }
__device__ __forceinline__ float tanh_(float v) { return 2.0f / (1.0f + __expf(-2.0f * v)) - 1.0f; }

// ---- prep: pack [W_hh | W_ih] rows into bf16 Wpack[2048][768] ----
__global__ __launch_bounds__(256) void build_wpack(const float* __restrict__ Whh,
                                                   const float* __restrict__ Wih,
                                                   unsigned short* __restrict__ wpack) {
    int idx = blockIdx.x * 256 + threadIdx.x;      // 0..196607, each = 8 elems
    int g = idx / 96, cc = idx % 96, k = cc * 8;
    const float* src = (k < H_) ? (Whh + (size_t)g * H_ + k)
                                : (Wih + (size_t)g * D_ + (k - H_));
    union { unsigned short us[8]; uint4 v; } u;
#pragma unroll
    for (int i = 0; i < 8; ++i) u.us[i] = f2bf(src[i]);
    *(uint4*)(wpack + (size_t)idx * 8) = u.v;
}

// ---- prep: zero h0/h1/c(+aliased flags), build bias ----
__global__ __launch_bounds__(256) void init_misc(const float* __restrict__ bih,
                                                 const float* __restrict__ bhh,
                                                 float* __restrict__ bias,
                                                 unsigned int* __restrict__ zreg,
                                                 unsigned int* __restrict__ flags) {
    int gid = blockIdx.x * 256 + threadIdx.x;      // grid 1024 -> 262144
    zreg[gid] = 0u;                                // h0+h1+c region (1 MB, covers flags)
    if (gid < G_) bias[gid] = bih[gid] + bhh[gid];
    if (gid < 16384) flags[gid] = 0u;
}

// ============ persistent cooperative LSTM ============
// grid 256: rg = bid&15 (rowgroup, 16 batch rows), cg = bid>>4 (32 j-cols).
// 512 threads = 8 waves; wave w: gate g = w>>1, K-half kh = w&1 (even/odd ks).
// Each wave reads ONE A-fragment per ks and issues 2 MFMAs (both 16-col
// j-tiles) -> E-phase As reads halved (r16-proven: conflicts 2.18e8->1.34e8).
// W fragments: 12 ks x 2 j-tiles = 24 bf16x8 = 96 VGPR, loaded once.
// c: 1 reg/thread.
// h protocol (r15-proven VERBATIM, 4 barriers/step):
//   producer tail: G epilogue -> Hs -> bar4 -> wave 0 stores the 1KB tile
//     (2x8B relaxed), drains ITS OWN vmcnt, publishes block flag IMMEDIATELY
//     (flag is on the inter-block chain -- r16's deferral was a regression).
//   consumer head: ALL waves poll the 16 block flags (relaxed), then load h
//     with sc0 sc1 (LLC-direct) -- no acquire, no inv, x stays cached.
// Pc[2][4][16][34] partial sums over kh; epilogue sums both halves (2-way).
// LDS padded (volatile) so 1 block/CU -> 256 blocks on 256 CUs.
__global__ __launch_bounds__(512, 2) void lstm_persist(
    const float* __restrict__ x,
    const unsigned short* __restrict__ wpack,
    const float* __restrict__ bias,
    unsigned short* __restrict__ h0,
    unsigned short* __restrict__ h1,
    unsigned int* __restrict__ flags)
{
    __shared__ __align__(16) unsigned char As[16 * 1536];   // [16 rows][768 k] bf16, swizzled
    __shared__ float Pc[2][4][16][34];                       // [kh][gate][row][j]
    __shared__ __align__(16) unsigned short Hs[16][32];      // new h tile (bf16)
    __shared__ unsigned char lds_pad[40 * 1024];             // force 1 block/CU

    const int tid  = threadIdx.x;
    const int lane = tid & 63, w = tid >> 6;
    const int g = w >> 1, kh = w & 1;
    const int rg = blockIdx.x & 15, cg = blockIdx.x >> 4;
    const int r0 = rg * 16;

    ((volatile unsigned char*)lds_pad)[tid] = 0;   // keep pad alive

    // ---- load this wave's W fragments (12 ks x 2 j-tiles), once ----
    bf16x8 bfr[24];
    {
#pragma unroll
        for (int i = 0; i < 12; ++i) {
            int ks = 2 * i + kh;
#pragma unroll
            for (int jt2 = 0; jt2 < 2; ++jt2) {
                const unsigned short* wrow = wpack
                    + (size_t)(g * H_ + cg * 32 + jt2 * 16 + (lane & 15)) * KT_
                    + ((lane >> 4) * 8) + ks * 32;
                bfr[i * 2 + jt2] = *(const bf16x8*)wrow;
            }
        }
    }

    // ---- per-thread epilogue constants (16 rows x 32 j = 512 threads) ----
    const int erow = tid >> 5;        // 0..15
    const int ejj  = tid & 31;        // 0..31
    const float bI = bias[0 * H_ + cg * 32 + ejj];
    const float bF = bias[1 * H_ + cg * 32 + ejj];
    const float bG = bias[2 * H_ + cg * 32 + ejj];
    const float bO = bias[3 * H_ + cg * 32 + ejj];
    float c_reg = 0.f;

    const int arow = lane & 15;            // A-tile row
    const int koff = (lane >> 4) * 16;     // byte offset within 64B k-step
    const int asw  = (arow & 7) << 4;

    // ---- x staging: all 512 threads, 1 chunk of 8 floats each (r15) ----
    const int xrow = tid >> 5;             // 0..15
    const int xseg = tid & 31;             // 0..31
    const float* xbase = x + (size_t)(r0 + xrow) * T_ * D_ + xseg * 8;
    float4 p0a = *(const float4*)(xbase);
    float4 p0b = *(const float4*)(xbase + 4);

    unsigned int* myflag   = flags + (size_t)(rg * 16 + cg) * 32;
    unsigned int* pollflag = flags + (size_t)(rg * 16 + (lane & 15)) * 32;

    for (int t = 0; t < T_; ++t) {
        const unsigned short* hin = (t & 1) ? h1 : h0;
        unsigned short*      hout = (t & 1) ? h0 : h1;

        // A: stage x(t) from prefetched regs -> As.x (k 512..767); prefetch x(t+1)
        {
            union { unsigned short us[8]; uint4 v; } u;
            u.us[0] = f2bf(p0a.x); u.us[1] = f2bf(p0a.y); u.us[2] = f2bf(p0a.z); u.us[3] = f2bf(p0a.w);
            u.us[4] = f2bf(p0b.x); u.us[5] = f2bf(p0b.y); u.us[6] = f2bf(p0b.z); u.us[7] = f2bf(p0b.w);
            *(uint4*)(As + ((xrow * 1536 + 1024 + xseg * 16) ^ ((xrow & 7) << 4))) = u.v;
        }
        if (t + 1 < T_) {
            const float* sp = xbase + (size_t)(t + 1) * D_;
            p0a = *(const float4*)(sp);
            p0b = *(const float4*)(sp + 4);
        }
        __syncthreads();   // bar1: As.x ready; orders E(t-1) reads vs D(t) writes

        // B1: x-part MFMAs, first half (i = 8,9 -> ks 16+kh, 18+kh)
        f32x4 acc[2][2];   // [jt2][i&1]
#pragma unroll
        for (int a = 0; a < 2; ++a) { acc[0][a] = (f32x4){0,0,0,0}; acc[1][a] = (f32x4){0,0,0,0}; }
#pragma unroll
        for (int i = 8; i < 10; ++i) {
            int ks = 2 * i + kh;
            bf16x8 av = *(const bf16x8*)(As + ((arow * 1536 + ks * 64 + koff) ^ asw));
            acc[0][i & 1] = __builtin_amdgcn_mfma_f32_16x16x32_bf16(av, bfr[i * 2 + 0], acc[0][i & 1], 0, 0, 0);
            acc[1][i & 1] = __builtin_amdgcn_mfma_f32_16x16x32_bf16(av, bfr[i * 2 + 1], acc[1][i & 1], 0, 0, 0);
        }

        // C: ALL waves poll the 16 block flags (relaxed; lanes 16-63 mirror).
        //    No acquire, no barrier: phase D uses LLC-direct loads.
        if (t > 0) {
            while (true) {
                unsigned int f = __hip_atomic_load(pollflag, __ATOMIC_RELAXED,
                                                   __HIP_MEMORY_SCOPE_AGENT);
                if (__all((int)(f >= (unsigned)t))) break;
                __builtin_amdgcn_s_sleep(1);
            }
        }

        // D: issue LLC-direct 16B h loads (2/thread, 16KB) into regs; overlap
        //    the remaining x-part MFMAs (i = 10,11); then stage to As.h.
        {
            u32x4 hv0, hv1;
            {
                int c = tid;                      // chunks 0..511
                int row = c >> 6, off = c & 63;
                const u32x4* pp0 = (const u32x4*)(hin + (size_t)(r0 + row) * H_ + off * 8);
                c = 512 + tid;
                row = c >> 6; off = c & 63;
                const u32x4* pp1 = (const u32x4*)(hin + (size_t)(r0 + row) * H_ + off * 8);
                asm volatile("global_load_dwordx4 %0, %2, off sc0 sc1\n\t"
                             "global_load_dwordx4 %1, %3, off sc0 sc1"
                             : "=&v"(hv0), "=&v"(hv1)
                             : "v"(pp0), "v"(pp1));
            }
#pragma unroll
            for (int i = 10; i < 12; ++i) {
                int ks = 2 * i + kh;
                bf16x8 av = *(const bf16x8*)(As + ((arow * 1536 + ks * 64 + koff) ^ asw));
                acc[0][i & 1] = __builtin_amdgcn_mfma_f32_16x16x32_bf16(av, bfr[i * 2 + 0], acc[0][i & 1], 0, 0, 0);
                acc[1][i & 1] = __builtin_amdgcn_mfma_f32_16x16x32_bf16(av, bfr[i * 2 + 1], acc[1][i & 1], 0, 0, 0);
            }
            asm volatile("s_waitcnt vmcnt(0)" ::: "memory");
            __builtin_amdgcn_sched_barrier(0);
            {
                int c = tid;
                int row = c >> 6, off = c & 63;
                *(u32x4*)(As + ((row * 1536 + off * 16) ^ ((row & 7) << 4))) = hv0;
                c = 512 + tid;
                row = c >> 6; off = c & 63;
                *(u32x4*)(As + ((row * 1536 + off * 16) ^ ((row & 7) << 4))) = hv1;
            }
        }
        __syncthreads();   // bar2: As.h ready

        // E: h-part MFMAs (i = 0..7 -> 8 ks of this K-half; 1 A-read, 2 MFMAs)
#pragma unroll
        for (int i = 0; i < 8; ++i) {
            int ks = 2 * i + kh;
            bf16x8 av = *(const bf16x8*)(As + ((arow * 1536 + ks * 64 + koff) ^ asw));
            acc[0][i & 1] = __builtin_amdgcn_mfma_f32_16x16x32_bf16(av, bfr[i * 2 + 0], acc[0][i & 1], 0, 0, 0);
            acc[1][i & 1] = __builtin_amdgcn_mfma_f32_16x16x32_bf16(av, bfr[i * 2 + 1], acc[1][i & 1], 0, 0, 0);
        }
        // F: dump partial gate tile (C layout: col=lane&15, row=(lane>>4)*4+reg)
#pragma unroll
        for (int reg = 0; reg < 4; ++reg) {
            int crow = ((lane >> 4) * 4) + reg;
            Pc[kh][g][crow][(lane & 15)]      = acc[0][0][reg] + acc[0][1][reg];
            Pc[kh][g][crow][16 + (lane & 15)] = acc[1][0][reg] + acc[1][1][reg];
        }
        __syncthreads();   // bar3: Pc ready

        // G: cell update; thread owns (erow, ejj); sum both K-halves;
        //    c stays in register; write h to Hs for the wave-0 tail.
        {
            float gi = Pc[0][0][erow][ejj] + Pc[1][0][erow][ejj] + bI;
            float gf = Pc[0][1][erow][ejj] + Pc[1][1][erow][ejj] + bF;
            float gg = Pc[0][2][erow][ejj] + Pc[1][2][erow][ejj] + bG;
            float go = Pc[0][3][erow][ejj] + Pc[1][3][erow][ejj] + bO;
            float I = sigm(gi), F = sigm(gf), Gv = tanh_(gg), O = sigm(go);
            c_reg = F * c_reg + I * Gv;
            Hs[erow][ejj] = f2bf(O * tanh_(c_reg));
        }
        __syncthreads();   // bar4: Hs ready

        // H: wave 0 alone stores the 1KB tile (16B/lane as 2x8B relaxed),
        //    drains ITS OWN vmcnt, publishes the flag IMMEDIATELY (r15).
        //    Waves 1-7 run ahead into next-step A (they only touch As.x).
        if (tid < 64) {
            int row = tid >> 2, part = tid & 3;
            const unsigned long long* src = (const unsigned long long*)(&Hs[row][part * 8]);
            unsigned long long v0 = src[0], v1 = src[1];
            unsigned long long* dst = (unsigned long long*)(hout + (size_t)(r0 + row) * H_ + cg * 32 + part * 8);
            __hip_atomic_store(dst,     v0, __ATOMIC_RELAXED, __HIP_MEMORY_SCOPE_AGENT);
            __hip_atomic_store(dst + 1, v1, __ATOMIC_RELAXED, __HIP_MEMORY_SCOPE_AGENT);
            asm volatile("s_waitcnt vmcnt(0)" ::: "memory");
            if (tid == 0)
                __hip_atomic_store(myflag, (unsigned)(t + 1), __ATOMIC_RELAXED,
                                   __HIP_MEMORY_SCOPE_AGENT);
        }
    }
}

// ============ fallback per-step kernel (round-1, known passing) ============
__global__ __launch_bounds__(256) void lstm_step(const float* __restrict__ x,
                                                 const unsigned short* __restrict__ wpack,
                                                 const float* __restrict__ bias,
                                                 const unsigned short* __restrict__ hin,
                                                 unsigned short* __restrict__ hout,
                                                 float* __restrict__ cbuf,
                                                 int t) {
    __shared__ __align__(16) unsigned char As[64 * 1536];
    __shared__ __align__(16) unsigned char Ws[128 * 256];

    const int tid = threadIdx.x;
    const int w = tid >> 6, lane = tid & 63;
    const int r0 = blockIdx.x * 64;
    const int j0 = blockIdx.y * 32;

#pragma unroll
    for (int p = 0; p < 16; ++p) {
        int idx = p * 256 + tid;
        int row = idx >> 6, seg = idx & 63;
        uint4 v = *(const uint4*)(hin + (size_t)(r0 + row) * H_ + seg * 8);
        *(uint4*)(As + (((row * 1536) + seg * 16) ^ ((row & 7) << 4))) = v;
    }
#pragma unroll
    for (int p = 0; p < 8; ++p) {
        int idx = p * 256 + tid;
        int row = idx >> 5, seg = idx & 31;
        const float* sp = x + ((size_t)(r0 + row) * T_ + t) * D_ + seg * 8;
        float4 a = *(const float4*)sp;
        float4 b = *(const float4*)(sp + 4);
        union { unsigned short us[8]; uint4 v; } u;
        u.us[0] = f2bf(a.x); u.us[1] = f2bf(a.y); u.us[2] = f2bf(a.z); u.us[3] = f2bf(a.w);
        u.us[4] = f2bf(b.x); u.us[5] = f2bf(b.y); u.us[6] = f2bf(b.z); u.us[7] = f2bf(b.w);
        *(uint4*)(As + (((row * 1536) + 1024 + seg * 16) ^ ((row & 7) << 4))) = u.v;
    }
    __syncthreads();

    f32x4 acc[8];
#pragma unroll
    for (int i = 0; i < 8; ++i) acc[i] = (f32x4){0.f, 0.f, 0.f, 0.f};

    for (int kc = 0; kc < 6; ++kc) {
#pragma unroll
        for (int p = 0; p < 8; ++p) {
            int idx = p * 256 + tid;
            int n = idx >> 4, seg = idx & 15;
            int g = n >> 5, jj = n & 31;
            uint4 v = *(const uint4*)(wpack + (size_t)(g * H_ + j0 + jj) * KT_ + kc * 128 + seg * 8);
            *(uint4*)(Ws + (((n * 256) + seg * 16) ^ ((n & 7) << 4))) = v;
        }
        __syncthreads();
#pragma unroll
        for (int ks = 0; ks < 4; ++ks) {
            int row = w * 16 + (lane & 15);
            int kb = (kc * 128 + ks * 32 + ((lane >> 4) * 8)) * 2;
            bf16x8 av = *(const bf16x8*)(As + ((row * 1536 + kb) ^ ((row & 7) << 4)));
            int kwb = (ks * 32 + ((lane >> 4) * 8)) * 2;
#pragma unroll
            for (int nt = 0; nt < 8; ++nt) {
                int n = (nt >> 1) * 32 + (nt & 1) * 16 + (lane & 15);
                bf16x8 bv = *(const bf16x8*)(Ws + ((n * 256 + kwb) ^ ((n & 7) << 4)));
                acc[nt] = __builtin_amdgcn_mfma_f32_16x16x32_bf16(av, bv, acc[nt], 0, 0, 0);
            }
        }
        __syncthreads();
    }

#pragma unroll
    for (int jt = 0; jt < 2; ++jt) {
        int jc = j0 + jt * 16 + (lane & 15);
        float bi = bias[jc], bf = bias[H_ + jc], bg = bias[2 * H_ + jc], bo = bias[3 * H_ + jc];
        f32x4 ai = acc[0 * 2 + jt];
        f32x4 af = acc[1 * 2 + jt];
        f32x4 ag = acc[2 * 2 + jt];
        f32x4 ao = acc[3 * 2 + jt];
#pragma unroll
        for (int reg = 0; reg < 4; ++reg) {
            int rb = r0 + w * 16 + ((lane >> 4) * 4) + reg;
            float I = sigm(ai[reg] + bi);
            float F = sigm(af[reg] + bf);
            float Gv = tanh_(ag[reg] + bg);
            float O = sigm(ao[reg] + bo);
            size_t ci = (size_t)rb * H_ + jc;
            float cn = F * cbuf[ci] + I * Gv;
            cbuf[ci] = cn;
            hout[ci] = f2bf(O * tanh_(cn));
        }
    }
}

// ---- final: out = sigmoid(h @ W_out^T + b_out), [256,2] ----
__global__ __launch_bounds__(256) void classify(const unsigned short* __restrict__ hbuf,
                                                const float* __restrict__ Wout,
                                                const float* __restrict__ bout,
                                                float* __restrict__ out) {
    int r = threadIdx.x;
    float a0 = 0.f, a1 = 0.f;
    for (int kk = 0; kk < H_ / 8; ++kk) {
        union { unsigned short us[8]; uint4 v; } u;
        u.v = *(const uint4*)(hbuf + (size_t)r * H_ + kk * 8);
#pragma unroll
        for (int i = 0; i < 8; ++i) {
            float hf = bf2f(u.us[i]);
            int k = kk * 8 + i;
            a0 += hf * Wout[k];
            a1 += hf * Wout[H_ + k];
        }
    }
    out[r * 2 + 0] = sigm(a0 + bout[0]);
    out[r * 2 + 1] = sigm(a1 + bout[1]);
}

extern "C" void kernel_launch(void* const* d_in, const int* in_sizes, int n_in,
                              void* d_out, int out_size, void* d_ws, size_t ws_size,
                              hipStream_t stream) {
    const float* x    = (const float*)d_in[0];
    const float* Wih  = (const float*)d_in[1];
    const float* Whh  = (const float*)d_in[2];
    const float* bih  = (const float*)d_in[3];
    const float* bhh  = (const float*)d_in[4];
    const float* Wout = (const float*)d_in[5];
    const float* bout = (const float*)d_in[6];
    float* out = (float*)d_out;
    char* ws = (char*)d_ws;

    unsigned short* wpack = (unsigned short*)(ws + WPACK_OFF);
    float*          bias  = (float*)(ws + BIAS_OFF);
    unsigned short* h0    = (unsigned short*)(ws + H0_OFF);
    unsigned short* h1    = (unsigned short*)(ws + H1_OFF);
    float*          cbuf  = (float*)(ws + C_OFF);
    unsigned int*   flags = (unsigned int*)(ws + FLAG_OFF);   // aliases cbuf (exclusive paths)

    build_wpack<<<768, 256, 0, stream>>>(Whh, Wih, wpack);
    init_misc<<<1024, 256, 0, stream>>>(bih, bhh, bias, (unsigned int*)(ws + H0_OFF), flags);

    // persistent cooperative kernel; fall back to per-step launches if rejected
    const float* xa = x; const unsigned short* wa = wpack; const float* ba = bias;
    unsigned short* h0a = h0; unsigned short* h1a = h1; unsigned int* fa = flags;
    void* args[] = { (void*)&xa, (void*)&wa, (void*)&ba, (void*)&h0a, (void*)&h1a, (void*)&fa };
    hipError_t e = hipLaunchCooperativeKernel((const void*)lstm_persist,
                                              dim3(256), dim3(512), args, 0, stream);
    if (e != hipSuccess) {
        for (int t = 0; t < T_; ++t) {
            const unsigned short* hin = (t & 1) ? h1 : h0;
            unsigned short*      hout = (t & 1) ? h0 : h1;
            lstm_step<<<dim3(4, 16), 256, 0, stream>>>(x, wpack, bias, hin, hout, cbuf, t);
        }
    }
    classify<<<1, 256, 0, stream>>>(h0, Wout, bout, out);
}

// Round 18
// 2449.846 us; speedup vs baseline: 1.3140x; 1.1030x over previous
//
#include <hip/hip_runtime.h>
#include <hip/hip_bf16.h>

#define B_  256
#define T_  1024
#define D_  256
#define H_  512
#define G_  2048   // 4*H
#define KT_ 768    // H + D

// ws layout (bytes)
#define WPACK_OFF 0                        // 2048*768*2 = 3145728
#define BIAS_OFF  3145728                  // 2048*4     = 8192
#define H0_OFF    (BIAS_OFF + 8192)        // 256*512*2  = 262144
#define H1_OFF    (H0_OFF + 262144)
#define C_OFF     (H1_OFF + 262144)        // 512KB: fallback cbuf
#define FLAG_OFF  C_OFF                    // flags alias cbuf (paths exclusive):
                                           // 256 flags x 32 uints = 32KB

typedef __attribute__((ext_vector_type(8))) short bf16x8;
typedef __attribute__((ext_vector_type(4))) float f32x4;
typedef __attribute__((ext_vector_type(4))) unsigned int u32x4;   // asm-safe 16B vector

__device__ __forceinline__ unsigned short f2bf(float f) {
    unsigned int u = __float_as_uint(f);
    u = (u + 0x7fffu + ((u >> 16) & 1u)) >> 16;   // RNE
    return (unsigned short)u;
}
__device__ __forceinline__ float bf2f(unsigned short s) {
    return __uint_as_float(((unsigned int)s) << 16);
}
__device__ __forceinline__ float sigm(float v) { return 1.0f / (1.0f + __expf(-v)); }
__device__ __forceinline__ float tanh_(float v) { return 2.0f / (1.0f + __expf(-2.0f * v)) - 1.0f; }

// ---- prep: pack [W_hh | W_ih] rows into bf16 Wpack[2048][768] ----
__global__ __launch_bounds__(256) void build_wpack(const float* __restrict__ Whh,
                                                   const float* __restrict__ Wih,
                                                   unsigned short* __restrict__ wpack) {
    int idx = blockIdx.x * 256 + threadIdx.x;      // 0..196607, each = 8 elems
    int g = idx / 96, cc = idx % 96, k = cc * 8;
    const float* src = (k < H_) ? (Whh + (size_t)g * H_ + k)
                                : (Wih + (size_t)g * D_ + (k - H_));
    union { unsigned short us[8]; uint4 v; } u;
#pragma unroll
    for (int i = 0; i < 8; ++i) u.us[i] = f2bf(src[i]);
    *(uint4*)(wpack + (size_t)idx * 8) = u.v;
}

// ---- prep: zero h0/h1/c(+aliased flags), build bias ----
__global__ __launch_bounds__(256) void init_misc(const float* __restrict__ bih,
                                                 const float* __restrict__ bhh,
                                                 float* __restrict__ bias,
                                                 unsigned int* __restrict__ zreg,
                                                 unsigned int* __restrict__ flags) {
    int gid = blockIdx.x * 256 + threadIdx.x;      // grid 1024 -> 262144
    zreg[gid] = 0u;                                // h0+h1+c region (1 MB, covers flags)
    if (gid < G_) bias[gid] = bih[gid] + bhh[gid];
    if (gid < 16384) flags[gid] = 0u;
}

// ============ persistent cooperative LSTM ============
// grid 256: rg = bid&15 (rowgroup, 16 batch rows), cg = bid>>4 (32 j-cols).
// 512 threads = 8 waves; wave w: gate g = w>>1, K-half kh = w&1 (even/odd ks).
// Each wave reads ONE A-fragment per ks and issues 2 MFMAs (both 16-col
// j-tiles) -> E-phase As reads halved (r16/r17-proven).
// W fragments: 12 ks x 2 j-tiles = 24 bf16x8 = 96 VGPR, loaded once.
// c: 1 reg/thread.
// h protocol (4 barriers/step):
//   producer tail (DIRECT STORE, this round): G computes h and stores its
//     own 2B value (relaxed agent) -- stores issue at G-end and drain IN
//     PARALLEL across all 8 waves inside bar4's per-wave vmcnt(0) drain;
//     tid 0 publishes the block flag right after bar4. ~200-300cy earlier
//     than the r17 wave-0/Hs tail, and 2B stores coalesce (WRITE_SIZE /2).
//   consumer head: ALL waves poll the 16 block flags (relaxed), then load h
//     with sc0 sc1 (LLC-direct) -- no acquire, no inv, x stays cached.
// Pc[2][4][16][34] partial sums over kh; epilogue sums both halves (2-way).
// LDS padded (volatile) so 1 block/CU -> 256 blocks on 256 CUs.
__global__ __launch_bounds__(512, 2) void lstm_persist(
    const float* __restrict__ x,
    const unsigned short* __restrict__ wpack,
    const float* __restrict__ bias,
    unsigned short* __restrict__ h0,
    unsigned short* __restrict__ h1,
    unsigned int* __restrict__ flags)
{
    __shared__ __align__(16) unsigned char As[16 * 1536];   // [16 rows][768 k] bf16, swizzled
    __shared__ float Pc[2][4][16][34];                       // [kh][gate][row][j]
    __shared__ unsigned char lds_pad[40 * 1024];             // force 1 block/CU

    const int tid  = threadIdx.x;
    const int lane = tid & 63, w = tid >> 6;
    const int g = w >> 1, kh = w & 1;
    const int rg = blockIdx.x & 15, cg = blockIdx.x >> 4;
    const int r0 = rg * 16;

    ((volatile unsigned char*)lds_pad)[tid] = 0;   // keep pad alive

    // ---- load this wave's W fragments (12 ks x 2 j-tiles), once ----
    bf16x8 bfr[24];
    {
#pragma unroll
        for (int i = 0; i < 12; ++i) {
            int ks = 2 * i + kh;
#pragma unroll
            for (int jt2 = 0; jt2 < 2; ++jt2) {
                const unsigned short* wrow = wpack
                    + (size_t)(g * H_ + cg * 32 + jt2 * 16 + (lane & 15)) * KT_
                    + ((lane >> 4) * 8) + ks * 32;
                bfr[i * 2 + jt2] = *(const bf16x8*)wrow;
            }
        }
    }

    // ---- per-thread epilogue constants (16 rows x 32 j = 512 threads) ----
    const int erow = tid >> 5;        // 0..15
    const int ejj  = tid & 31;        // 0..31
    const float bI = bias[0 * H_ + cg * 32 + ejj];
    const float bF = bias[1 * H_ + cg * 32 + ejj];
    const float bG = bias[2 * H_ + cg * 32 + ejj];
    const float bO = bias[3 * H_ + cg * 32 + ejj];
    float c_reg = 0.f;

    const int arow = lane & 15;            // A-tile row
    const int koff = (lane >> 4) * 16;     // byte offset within 64B k-step
    const int asw  = (arow & 7) << 4;

    // ---- x staging: all 512 threads, 1 chunk of 8 floats each ----
    const int xrow = tid >> 5;             // 0..15
    const int xseg = tid & 31;             // 0..31
    const float* xbase = x + (size_t)(r0 + xrow) * T_ * D_ + xseg * 8;
    float4 p0a = *(const float4*)(xbase);
    float4 p0b = *(const float4*)(xbase + 4);

    unsigned int* myflag   = flags + (size_t)(rg * 16 + cg) * 32;
    unsigned int* pollflag = flags + (size_t)(rg * 16 + (lane & 15)) * 32;

    for (int t = 0; t < T_; ++t) {
        const unsigned short* hin = (t & 1) ? h1 : h0;
        unsigned short*      hout = (t & 1) ? h0 : h1;

        // A: stage x(t) from prefetched regs -> As.x (k 512..767); prefetch x(t+1)
        {
            union { unsigned short us[8]; uint4 v; } u;
            u.us[0] = f2bf(p0a.x); u.us[1] = f2bf(p0a.y); u.us[2] = f2bf(p0a.z); u.us[3] = f2bf(p0a.w);
            u.us[4] = f2bf(p0b.x); u.us[5] = f2bf(p0b.y); u.us[6] = f2bf(p0b.z); u.us[7] = f2bf(p0b.w);
            *(uint4*)(As + ((xrow * 1536 + 1024 + xseg * 16) ^ ((xrow & 7) << 4))) = u.v;
        }
        if (t + 1 < T_) {
            const float* sp = xbase + (size_t)(t + 1) * D_;
            p0a = *(const float4*)(sp);
            p0b = *(const float4*)(sp + 4);
        }
        __syncthreads();   // bar1: As.x ready; orders E(t-1) reads vs D(t) writes

        // B1: x-part MFMAs, first half (i = 8,9 -> ks 16+kh, 18+kh)
        f32x4 acc[2][2];   // [jt2][i&1]
#pragma unroll
        for (int a = 0; a < 2; ++a) { acc[0][a] = (f32x4){0,0,0,0}; acc[1][a] = (f32x4){0,0,0,0}; }
#pragma unroll
        for (int i = 8; i < 10; ++i) {
            int ks = 2 * i + kh;
            bf16x8 av = *(const bf16x8*)(As + ((arow * 1536 + ks * 64 + koff) ^ asw));
            acc[0][i & 1] = __builtin_amdgcn_mfma_f32_16x16x32_bf16(av, bfr[i * 2 + 0], acc[0][i & 1], 0, 0, 0);
            acc[1][i & 1] = __builtin_amdgcn_mfma_f32_16x16x32_bf16(av, bfr[i * 2 + 1], acc[1][i & 1], 0, 0, 0);
        }

        // C: ALL waves poll the 16 block flags (relaxed; lanes 16-63 mirror).
        if (t > 0) {
            while (true) {
                unsigned int f = __hip_atomic_load(pollflag, __ATOMIC_RELAXED,
                                                   __HIP_MEMORY_SCOPE_AGENT);
                if (__all((int)(f >= (unsigned)t))) break;
                __builtin_amdgcn_s_sleep(1);
            }
        }

        // D: issue LLC-direct 16B h loads (2/thread, 16KB) into regs; overlap
        //    the remaining x-part MFMAs (i = 10,11); then stage to As.h.
        {
            u32x4 hv0, hv1;
            {
                int c = tid;                      // chunks 0..511
                int row = c >> 6, off = c & 63;
                const u32x4* pp0 = (const u32x4*)(hin + (size_t)(r0 + row) * H_ + off * 8);
                c = 512 + tid;
                row = c >> 6; off = c & 63;
                const u32x4* pp1 = (const u32x4*)(hin + (size_t)(r0 + row) * H_ + off * 8);
                asm volatile("global_load_dwordx4 %0, %2, off sc0 sc1\n\t"
                             "global_load_dwordx4 %1, %3, off sc0 sc1"
                             : "=&v"(hv0), "=&v"(hv1)
                             : "v"(pp0), "v"(pp1));
            }
#pragma unroll
            for (int i = 10; i < 12; ++i) {
                int ks = 2 * i + kh;
                bf16x8 av = *(const bf16x8*)(As + ((arow * 1536 + ks * 64 + koff) ^ asw));
                acc[0][i & 1] = __builtin_amdgcn_mfma_f32_16x16x32_bf16(av, bfr[i * 2 + 0], acc[0][i & 1], 0, 0, 0);
                acc[1][i & 1] = __builtin_amdgcn_mfma_f32_16x16x32_bf16(av, bfr[i * 2 + 1], acc[1][i & 1], 0, 0, 0);
            }
            asm volatile("s_waitcnt vmcnt(0)" ::: "memory");
            __builtin_amdgcn_sched_barrier(0);
            {
                int c = tid;
                int row = c >> 6, off = c & 63;
                *(u32x4*)(As + ((row * 1536 + off * 16) ^ ((row & 7) << 4))) = hv0;
                c = 512 + tid;
                row = c >> 6; off = c & 63;
                *(u32x4*)(As + ((row * 1536 + off * 16) ^ ((row & 7) << 4))) = hv1;
            }
        }
        __syncthreads();   // bar2: As.h ready

        // E: h-part MFMAs (i = 0..7 -> 8 ks of this K-half; 1 A-read, 2 MFMAs)
#pragma unroll
        for (int i = 0; i < 8; ++i) {
            int ks = 2 * i + kh;
            bf16x8 av = *(const bf16x8*)(As + ((arow * 1536 + ks * 64 + koff) ^ asw));
            acc[0][i & 1] = __builtin_amdgcn_mfma_f32_16x16x32_bf16(av, bfr[i * 2 + 0], acc[0][i & 1], 0, 0, 0);
            acc[1][i & 1] = __builtin_amdgcn_mfma_f32_16x16x32_bf16(av, bfr[i * 2 + 1], acc[1][i & 1], 0, 0, 0);
        }
        // F: dump partial gate tile (C layout: col=lane&15, row=(lane>>4)*4+reg)
#pragma unroll
        for (int reg = 0; reg < 4; ++reg) {
            int crow = ((lane >> 4) * 4) + reg;
            Pc[kh][g][crow][(lane & 15)]      = acc[0][0][reg] + acc[0][1][reg];
            Pc[kh][g][crow][16 + (lane & 15)] = acc[1][0][reg] + acc[1][1][reg];
        }
        __syncthreads();   // bar3: Pc ready

        // G: cell update; thread owns (erow, ejj); sum both K-halves; c stays
        //    in register; store h DIRECTLY (2B relaxed agent) -- drains in
        //    parallel across waves inside bar4's per-wave vmcnt(0).
        {
            float gi = Pc[0][0][erow][ejj] + Pc[1][0][erow][ejj] + bI;
            float gf = Pc[0][1][erow][ejj] + Pc[1][1][erow][ejj] + bF;
            float gg = Pc[0][2][erow][ejj] + Pc[1][2][erow][ejj] + bG;
            float go = Pc[0][3][erow][ejj] + Pc[1][3][erow][ejj] + bO;
            float I = sigm(gi), F = sigm(gf), Gv = tanh_(gg), O = sigm(go);
            c_reg = F * c_reg + I * Gv;
            unsigned short hv16 = f2bf(O * tanh_(c_reg));
            __hip_atomic_store(hout + (size_t)(r0 + erow) * H_ + cg * 32 + ejj,
                               hv16, __ATOMIC_RELAXED, __HIP_MEMORY_SCOPE_AGENT);
        }
        __syncthreads();   // bar4: all waves' h stores drained (vmcnt(0) each)

        // H: publish the block flag immediately (stores already at LLC).
        if (tid == 0)
            __hip_atomic_store(myflag, (unsigned)(t + 1), __ATOMIC_RELAXED,
                               __HIP_MEMORY_SCOPE_AGENT);
    }
}

// ============ fallback per-step kernel (round-1, known passing) ============
__global__ __launch_bounds__(256) void lstm_step(const float* __restrict__ x,
                                                 const unsigned short* __restrict__ wpack,
                                                 const float* __restrict__ bias,
                                                 const unsigned short* __restrict__ hin,
                                                 unsigned short* __restrict__ hout,
                                                 float* __restrict__ cbuf,
                                                 int t) {
    __shared__ __align__(16) unsigned char As[64 * 1536];
    __shared__ __align__(16) unsigned char Ws[128 * 256];

    const int tid = threadIdx.x;
    const int w = tid >> 6, lane = tid & 63;
    const int r0 = blockIdx.x * 64;
    const int j0 = blockIdx.y * 32;

#pragma unroll
    for (int p = 0; p < 16; ++p) {
        int idx = p * 256 + tid;
        int row = idx >> 6, seg = idx & 63;
        uint4 v = *(const uint4*)(hin + (size_t)(r0 + row) * H_ + seg * 8);
        *(uint4*)(As + (((row * 1536) + seg * 16) ^ ((row & 7) << 4))) = v;
    }
#pragma unroll
    for (int p = 0; p < 8; ++p) {
        int idx = p * 256 + tid;
        int row = idx >> 5, seg = idx & 31;
        const float* sp = x + ((size_t)(r0 + row) * T_ + t) * D_ + seg * 8;
        float4 a = *(const float4*)sp;
        float4 b = *(const float4*)(sp + 4);
        union { unsigned short us[8]; uint4 v; } u;
        u.us[0] = f2bf(a.x); u.us[1] = f2bf(a.y); u.us[2] = f2bf(a.z); u.us[3] = f2bf(a.w);
        u.us[4] = f2bf(b.x); u.us[5] = f2bf(b.y); u.us[6] = f2bf(b.z); u.us[7] = f2bf(b.w);
        *(uint4*)(As + (((row * 1536) + 1024 + seg * 16) ^ ((row & 7) << 4))) = u.v;
    }
    __syncthreads();

    f32x4 acc[8];
#pragma unroll
    for (int i = 0; i < 8; ++i) acc[i] = (f32x4){0.f, 0.f, 0.f, 0.f};

    for (int kc = 0; kc < 6; ++kc) {
#pragma unroll
        for (int p = 0; p < 8; ++p) {
            int idx = p * 256 + tid;
            int n = idx >> 4, seg = idx & 15;
            int g = n >> 5, jj = n & 31;
            uint4 v = *(const uint4*)(wpack + (size_t)(g * H_ + j0 + jj) * KT_ + kc * 128 + seg * 8);
            *(uint4*)(Ws + (((n * 256) + seg * 16) ^ ((n & 7) << 4))) = v;
        }
        __syncthreads();
#pragma unroll
        for (int ks = 0; ks < 4; ++ks) {
            int row = w * 16 + (lane & 15);
            int kb = (kc * 128 + ks * 32 + ((lane >> 4) * 8)) * 2;
            bf16x8 av = *(const bf16x8*)(As + ((row * 1536 + kb) ^ ((row & 7) << 4)));
            int kwb = (ks * 32 + ((lane >> 4) * 8)) * 2;
#pragma unroll
            for (int nt = 0; nt < 8; ++nt) {
                int n = (nt >> 1) * 32 + (nt & 1) * 16 + (lane & 15);
                bf16x8 bv = *(const bf16x8*)(Ws + ((n * 256 + kwb) ^ ((n & 7) << 4)));
                acc[nt] = __builtin_amdgcn_mfma_f32_16x16x32_bf16(av, bv, acc[nt], 0, 0, 0);
            }
        }
        __syncthreads();
    }

#pragma unroll
    for (int jt = 0; jt < 2; ++jt) {
        int jc = j0 + jt * 16 + (lane & 15);
        float bi = bias[jc], bf = bias[H_ + jc], bg = bias[2 * H_ + jc], bo = bias[3 * H_ + jc];
        f32x4 ai = acc[0 * 2 + jt];
        f32x4 af = acc[1 * 2 + jt];
        f32x4 ag = acc[2 * 2 + jt];
        f32x4 ao = acc[3 * 2 + jt];
#pragma unroll
        for (int reg = 0; reg < 4; ++reg) {
            int rb = r0 + w * 16 + ((lane >> 4) * 4) + reg;
            float I = sigm(ai[reg] + bi);
            float F = sigm(af[reg] + bf);
            float Gv = tanh_(ag[reg] + bg);
            float O = sigm(ao[reg] + bo);
            size_t ci = (size_t)rb * H_ + jc;
            float cn = F * cbuf[ci] + I * Gv;
            cbuf[ci] = cn;
            hout[ci] = f2bf(O * tanh_(cn));
        }
    }
}

// ---- final: out = sigmoid(h @ W_out^T + b_out), [256,2] ----
__global__ __launch_bounds__(256) void classify(const unsigned short* __restrict__ hbuf,
                                                const float* __restrict__ Wout,
                                                const float* __restrict__ bout,
                                                float* __restrict__ out) {
    int r = threadIdx.x;
    float a0 = 0.f, a1 = 0.f;
    for (int kk = 0; kk < H_ / 8; ++kk) {
        union { unsigned short us[8]; uint4 v; } u;
        u.v = *(const uint4*)(hbuf + (size_t)r * H_ + kk * 8);
#pragma unroll
        for (int i = 0; i < 8; ++i) {
            float hf = bf2f(u.us[i]);
            int k = kk * 8 + i;
            a0 += hf * Wout[k];
            a1 += hf * Wout[H_ + k];
        }
    }
    out[r * 2 + 0] = sigm(a0 + bout[0]);
    out[r * 2 + 1] = sigm(a1 + bout[1]);
}

extern "C" void kernel_launch(void* const* d_in, const int* in_sizes, int n_in,
                              void* d_out, int out_size, void* d_ws, size_t ws_size,
                              hipStream_t stream) {
    const float* x    = (const float*)d_in[0];
    const float* Wih  = (const float*)d_in[1];
    const float* Whh  = (const float*)d_in[2];
    const float* bih  = (const float*)d_in[3];
    const float* bhh  = (const float*)d_in[4];
    const float* Wout = (const float*)d_in[5];
    const float* bout = (const float*)d_in[6];
    float* out = (float*)d_out;
    char* ws = (char*)d_ws;

    unsigned short* wpack = (unsigned short*)(ws + WPACK_OFF);
    float*          bias  = (float*)(ws + BIAS_OFF);
    unsigned short* h0    = (unsigned short*)(ws + H0_OFF);
    unsigned short* h1    = (unsigned short*)(ws + H1_OFF);
    float*          cbuf  = (float*)(ws + C_OFF);
    unsigned int*   flags = (unsigned int*)(ws + FLAG_OFF);   // aliases cbuf (exclusive paths)

    build_wpack<<<768, 256, 0, stream>>>(Whh, Wih, wpack);
    init_misc<<<1024, 256, 0, stream>>>(bih, bhh, bias, (unsigned int*)(ws + H0_OFF), flags);

    // persistent cooperative kernel; fall back to per-step launches if rejected
    const float* xa = x; const unsigned short* wa = wpack; const float* ba = bias;
    unsigned short* h0a = h0; unsigned short* h1a = h1; unsigned int* fa = flags;
    void* args[] = { (void*)&xa, (void*)&wa, (void*)&ba, (void*)&h0a, (void*)&h1a, (void*)&fa };
    hipError_t e = hipLaunchCooperativeKernel((const void*)lstm_persist,
                                              dim3(256), dim3(512), args, 0, stream);
    if (e != hipSuccess) {
        for (int t = 0; t < T_; ++t) {
            const unsigned short* hin = (t & 1) ? h1 : h0;
            unsigned short*      hout = (t & 1) ? h0 : h1;
            lstm_step<<<dim3(4, 16), 256, 0, stream>>>(x, wpack, bias, hin, hout, cbuf, t);
        }
    }
    classify<<<1, 256, 0, stream>>>(h0, Wout, bout, out);
}